// Round 6
// baseline (743.996 us; speedup 1.0000x reference)
//
#include <hip/hip_runtime.h>

// LevelwiseSTA v6: big-chunk rank-free multisplit + LDS-local two-phase LSE.
// Round-5 lessons: (a) 8000 buckets x 4096-edge chunks -> 0.5 rec/bucket/chunk
// -> cross-XCD partial-line writes (322MB) + per-chunk LDS zero/scan overhead;
// (b) the LDS-local chain (~8us/level) is the right structure. v6 keeps the
// chain, rebuilds stage1: CHUNK=32768 (one per block, 512 thr), NBK=4000
// (BN=250), and a rank-free 3-pass (count -> reserve -> re-read dst +
// LDS-cursor atomicAdd for the exact slot) so no per-edge rank registers.
//
// Invalid d = bf16(-3e30) sentinel: loses every max, underflows every exp;
// max <= -1e29 -> NEG_INF; fp32 absorption (-1e30 + d == -1e30) keeps
// reachability classification exactly equal to the reference.

#define NEG_INF  (-1e30f)
#define TAU_F    (0.07f)
#define INV_TAU  (1.0f / 0.07f)
#define BN    250         // nodes per bucket (31250 % 250 == 0)
#define GPL   125         // buckets per level
#define NBK   4000        // total buckets = 1M / 250
#define CHUNK 32768

typedef unsigned int uint;

__device__ __forceinline__ uint bf16_of(float f) {
    uint u = __float_as_uint(f);
    u += 0x7FFFu + ((u >> 16) & 1u);    // round to nearest even
    return u >> 16;
}
__device__ __forceinline__ float f_of_bf16(uint h) {
    return __uint_as_float((h & 0xFFFFu) << 16);
}
// monotone float<->uint; enc() != 0 for any real float, 0 == "empty"
__device__ __forceinline__ uint enc_f(float f) {
    uint u = __float_as_uint(f);
    return (u & 0x80000000u) ? ~u : (u | 0x80000000u);
}
__device__ __forceinline__ float dec_f(uint e) {
    uint u = (e & 0x80000000u) ? (e & 0x7FFFFFFFu) : ~e;
    return __uint_as_float(u);
}

// ---------------------------------------------------------------- histogram
__global__ __launch_bounds__(256) void k_hist(const int* __restrict__ dst, int E,
                                              int* __restrict__ cnt) {
    __shared__ int h[NBK];
    for (int k = threadIdx.x; k < NBK; k += 256) h[k] = 0;
    __syncthreads();
    int i = blockIdx.x * 256 + threadIdx.x, st = gridDim.x * 256;
    for (; i < E; i += st) atomicAdd(&h[dst[i] / BN], 1);
    __syncthreads();
    for (int k = threadIdx.x; k < NBK; k += 256)
        if (h[k]) atomicAdd(&cnt[k], h[k]);
}

// --------------------------------------------------------------------- scan
__global__ __launch_bounds__(1024) void k_scan(const int* __restrict__ cnt,
                                               int* __restrict__ base,
                                               int* __restrict__ cur) {
    __shared__ int sd[1024];
    int t = threadIdx.x;
    int v[4]; int tot = 0;
#pragma unroll
    for (int k = 0; k < 4; ++k) {
        int i = t * 4 + k;
        v[k] = (i < NBK) ? cnt[i] : 0;
        tot += v[k];
    }
    sd[t] = tot; __syncthreads();
    for (int o = 1; o < 1024; o <<= 1) {
        int x = 0; if (t >= o) x = sd[t - o];
        __syncthreads();
        sd[t] += x;
        __syncthreads();
    }
    int excl = sd[t] - tot;
#pragma unroll
    for (int k = 0; k < 4; ++k) {
        int i = t * 4 + k;
        if (i < NBK) { base[i] = excl; cur[i] = excl; }
        excl += v[k];
    }
    if (t == 1023) base[NBK] = sd[1023];
}

// ------------------------------------------------------------------- stage1
// One 32768-edge chunk per block, 512 threads. Pass A: LDS bucket count.
// Pass B: reserve global windows (LDS count -> global cursor base, in place).
// Pass C: re-read dst (L2-hot), LDS-cursor atomicAdd = exact packed slot,
// convert d to bf16 (invalid -> sentinel), write 16B record.
__global__ __launch_bounds__(512) void k_stage1(
        const int* __restrict__ srcA, const int* __restrict__ dstA,
        const float4* __restrict__ dh, const float4* __restrict__ mk,
        int E, int* __restrict__ cur, uint4* __restrict__ recs) {
    __shared__ int h[NBK];
    const int t = threadIdx.x;
    const int bb = blockIdx.x * CHUNK;
    for (int k = t; k < NBK; k += 512) h[k] = 0;
    __syncthreads();
#pragma unroll 4
    for (int k = 0; k < CHUNK / 512; ++k) {
        int i = bb + k * 512 + t;
        if (i < E) atomicAdd(&h[dstA[i] / BN], 1);
    }
    __syncthreads();
    for (int k = t; k < NBK; k += 512) {
        int cc = h[k];
        if (cc) h[k] = atomicAdd(&cur[k], cc);   // count -> global cursor base
    }
    __syncthreads();
    const uint INVB = bf16_of(-3e30f);
    for (int k = 0; k < CHUNK / 512; ++k) {
        int i = bb + k * 512 + t;
        if (i >= E) continue;
        int d = dstA[i];
        int b = d / BN;
        int pos = atomicAdd(&h[b], 1);
        float4 dv = dh[i];
        float4 mv = mk[i];
        uint e0 = (mv.x > 0.5f) ? bf16_of(dv.x * mv.x) : INVB;
        uint e1 = (mv.y > 0.5f) ? bf16_of(dv.y * mv.y) : INVB;
        uint e2 = (mv.z > 0.5f) ? bf16_of(dv.z * mv.z) : INVB;
        uint e3 = (mv.w > 0.5f) ? bf16_of(dv.w * mv.w) : INVB;
        uint4 r;
        r.x = (uint)srcA[i];
        r.y = (uint)(d - b * BN);
        r.z = e0 | (e1 << 16);
        r.w = e2 | (e3 << 16);
        recs[pos] = r;
    }
}

// -------------------------------------------------------------- level kernel
// One block per bucket (250 nodes), 512 threads. Pass 1: LDS atomicMax per
// node/channel. Pass 2: re-read records (L1/L2-hot), LDS atomicAdd of
// exp((v-m)/tau). Finalize: at = m + tau*log(s) or NEG_INF.
__global__ __launch_bounds__(512) void k_level(
        const uint4* __restrict__ recs, const int* __restrict__ base,
        float* __restrict__ at, int lvl) {
    int b = lvl * GPL + blockIdx.x;
    int j0 = base[b], j1 = base[b + 1];
    __shared__ uint  lm[BN * 2];
    __shared__ float ls[BN * 2];
    int t = threadIdx.x;
    for (int k = t; k < BN * 2; k += 512) { lm[k] = 0u; ls[k] = 0.f; }
    __syncthreads();
    for (int j = j0 + t; j < j1; j += 512) {
        uint4 r = recs[j];
        float2 a = *(const float2*)(at + 2 * (size_t)r.x);
        float cr0 = a.x + f_of_bf16(r.z);
        float cf0 = a.x + f_of_bf16(r.z >> 16);
        float cr1 = a.y + f_of_bf16(r.w);
        float cf1 = a.y + f_of_bf16(r.w >> 16);
        int n2 = 2 * (int)r.y;
        atomicMax(&lm[n2],     max(enc_f(cr0), enc_f(cr1)));
        atomicMax(&lm[n2 + 1], max(enc_f(cf0), enc_f(cf1)));
    }
    __syncthreads();
    for (int j = j0 + t; j < j1; j += 512) {
        uint4 r = recs[j];
        float2 a = *(const float2*)(at + 2 * (size_t)r.x);
        float cr0 = a.x + f_of_bf16(r.z);
        float cf0 = a.x + f_of_bf16(r.z >> 16);
        float cr1 = a.y + f_of_bf16(r.w);
        float cf1 = a.y + f_of_bf16(r.w >> 16);
        int n2 = 2 * (int)r.y;
        float mr = dec_f(lm[n2]);
        atomicAdd(&ls[n2], __expf((cr0 - mr) * INV_TAU) + __expf((cr1 - mr) * INV_TAU));
        float mf = dec_f(lm[n2 + 1]);
        atomicAdd(&ls[n2 + 1], __expf((cf0 - mf) * INV_TAU) + __expf((cf1 - mf) * INV_TAU));
    }
    __syncthreads();
    size_t obase = (size_t)b * (BN * 2);
    for (int k = t; k < BN * 2; k += 512) {
        uint e = lm[k];
        float v = NEG_INF;
        if (e != 0u) {
            float m = dec_f(e);
            if (m > -1e29f) v = m + TAU_F * __logf(ls[k]);
        }
        at[obase + k] = v;
    }
}

// -------------------------------------------------------------------- init
__global__ void k_init(const float2* __restrict__ ia, float2* __restrict__ at2,
                       int per) {
    int i = blockIdx.x * blockDim.x + threadIdx.x;
    if (i < per) at2[i] = ia[i];
}

// ---------------------------------------------------------------- endpoints
__global__ void k_ep(const float2* __restrict__ at2, const int* __restrict__ ep,
                     const float* __restrict__ rat, int M,
                     float* __restrict__ out_ep, float* __restrict__ out_slack) {
    int i = blockIdx.x * blockDim.x + threadIdx.x;
    int st = gridDim.x * blockDim.x;
    const float thr = NEG_INF + 1.0f;   // == -1e30f in fp32
    for (; i < M; i += st) {
        float2 a = at2[ep[i]];
        float sx = (a.x > thr) ? a.x : 0.f;
        float sy = (a.y > thr) ? a.y : 0.f;
        out_ep[2 * i]        = sx;
        out_ep[2 * i + 1]    = sy;
        out_slack[2 * i]     = rat[2 * i]     - sx;
        out_slack[2 * i + 1] = rat[2 * i + 1] - sy;
    }
}

extern "C" void kernel_launch(void* const* d_in, const int* in_sizes, int n_in,
                              void* d_out, int out_size, void* d_ws, size_t ws_size,
                              hipStream_t stream) {
    const float* d_hat         = (const float*)d_in[0];
    const float* sta_mask      = (const float*)d_in[1];
    const float* input_arrival = (const float*)d_in[2];
    const float* rat_true      = (const float*)d_in[3];
    const int*   edge_src      = (const int*)d_in[4];
    const int*   edge_dst      = (const int*)d_in[5];
    const int*   endpoint_ids  = (const int*)d_in[6];

    const int E = in_sizes[4];
    const int N = in_sizes[2] / 2;
    const int M = in_sizes[3] / 2;
    const int L = 32;                 // max_level = 31
    const int per = N / L;
    (void)n_in; (void)out_size; (void)ws_size;

    char* ws = (char*)d_ws;
    size_t off = 0;
    auto alloc = [&](size_t bytes) {
        void* p = ws + off;
        off = (off + bytes + 255) & ~((size_t)255);
        return p;
    };
    int*   cnt  = (int*)alloc((size_t)NBK * 4);
    int*   base = (int*)alloc((size_t)(NBK + 1) * 4);
    int*   cur  = (int*)alloc((size_t)NBK * 4);
    uint4* recs = (uint4*)alloc((size_t)E * 16);   // 128 MB, packed exactly

    float* at        = (float*)d_out;              // at_all doubles as state
    float* out_ep    = at + 2 * (size_t)N;
    float* out_slack = out_ep + 2 * (size_t)M;

    hipMemsetAsync(cnt, 0, (size_t)NBK * 4, stream);
    k_init<<<(per + 255) / 256, 256, 0, stream>>>((const float2*)input_arrival,
                                                  (float2*)at, per);
    k_hist<<<1024, 256, 0, stream>>>(edge_dst, E, cnt);
    k_scan<<<1, 1024, 0, stream>>>(cnt, base, cur);

    int nChunk = (E + CHUNK - 1) / CHUNK;
    k_stage1<<<nChunk, 512, 0, stream>>>(edge_src, edge_dst,
                                         (const float4*)d_hat, (const float4*)sta_mask,
                                         E, cur, recs);

    for (int lvl = 1; lvl < L; ++lvl)
        k_level<<<GPL, 512, 0, stream>>>(recs, base, at, lvl);

    k_ep<<<(M + 255) / 256, 256, 0, stream>>>((const float2*)at, endpoint_ids,
                                              rat_true, M, out_ep, out_slack);
}

// Round 7
// 516.130 us; speedup vs baseline: 1.4415x; 1.4415x over previous
//
#include <hip/hip_runtime.h>

// LevelwiseSTA v7: high-occupancy multisplit + single-pass register-stash chain.
// Round-6 lessons: (a) stage1 at 245 blocks x 512thr = 8 waves/CU was
// latency-bound at 21% occupancy -> 1024 threads doubles waves/CU;
// (b) chain wants MANY blocks (250 >> 125); (c) chain's 2nd pass re-gathered
// at[src] (line-amplified) -> stash candidates in statically-indexed registers
// (KPT=3 x 512thr = 1536 >= +16sigma of bucket count; dynamic tail never runs).
//
// Invalid d = bf16(-3e30) sentinel: loses every max, underflows every exp;
// max <= -1e29 -> NEG_INF; fp32 absorption (-1e30 + d == -1e30) keeps
// reachability classification exactly equal to the reference.

#define NEG_INF  (-1e30f)
#define TAU_F    (0.07f)
#define INV_TAU  (1.0f / 0.07f)
#define BN    125         // nodes per bucket
#define GPL   250         // buckets (blocks) per level
#define NBK   8000        // total buckets = 1M / 125
#define CHUNK 32768
#define KPT   3           // stashed records per thread in chain (512 thr)

typedef unsigned int uint;

__device__ __forceinline__ uint bf16_of(float f) {
    uint u = __float_as_uint(f);
    u += 0x7FFFu + ((u >> 16) & 1u);    // round to nearest even
    return u >> 16;
}
__device__ __forceinline__ float f_of_bf16(uint h) {
    return __uint_as_float((h & 0xFFFFu) << 16);
}
// monotone float<->uint; enc() != 0 for any real float, 0 == "empty"
__device__ __forceinline__ uint enc_f(float f) {
    uint u = __float_as_uint(f);
    return (u & 0x80000000u) ? ~u : (u | 0x80000000u);
}
__device__ __forceinline__ float dec_f(uint e) {
    uint u = (e & 0x80000000u) ? (e & 0x7FFFFFFFu) : ~e;
    return __uint_as_float(u);
}

// ---------------------------------------------------------------- histogram
__global__ __launch_bounds__(256) void k_hist(const int* __restrict__ dst, int E,
                                              int* __restrict__ cnt) {
    __shared__ int h[NBK];
    for (int k = threadIdx.x; k < NBK; k += 256) h[k] = 0;
    __syncthreads();
    int i = blockIdx.x * 256 + threadIdx.x, st = gridDim.x * 256;
    for (; i < E; i += st) atomicAdd(&h[dst[i] / BN], 1);
    __syncthreads();
    for (int k = threadIdx.x; k < NBK; k += 256)
        if (h[k]) atomicAdd(&cnt[k], h[k]);
}

// --------------------------------------------------------------------- scan
__global__ __launch_bounds__(1024) void k_scan(const int* __restrict__ cnt,
                                               int* __restrict__ base,
                                               int* __restrict__ cur) {
    __shared__ int sd[1024];
    int t = threadIdx.x;
    int v[8]; int tot = 0;
#pragma unroll
    for (int k = 0; k < 8; ++k) {
        int i = t * 8 + k;
        v[k] = (i < NBK) ? cnt[i] : 0;
        tot += v[k];
    }
    sd[t] = tot; __syncthreads();
    for (int o = 1; o < 1024; o <<= 1) {
        int x = 0; if (t >= o) x = sd[t - o];
        __syncthreads();
        sd[t] += x;
        __syncthreads();
    }
    int excl = sd[t] - tot;
#pragma unroll
    for (int k = 0; k < 8; ++k) {
        int i = t * 8 + k;
        if (i < NBK) { base[i] = excl; cur[i] = excl; }
        excl += v[k];
    }
    if (t == 1023) base[NBK] = sd[1023];
}

// ------------------------------------------------------------------- stage1
// One 32768-edge chunk per block, 1024 threads (16 waves/CU). Pass A: LDS
// bucket count. Pass B: reserve global windows. Pass C: re-read dst (L2-hot),
// LDS-cursor atomicAdd = exact packed slot, write 16B record.
__global__ __launch_bounds__(1024) void k_stage1(
        const int* __restrict__ srcA, const int* __restrict__ dstA,
        const float4* __restrict__ dh, const float4* __restrict__ mk,
        int E, int* __restrict__ cur, uint4* __restrict__ recs) {
    __shared__ int h[NBK];
    const int t = threadIdx.x;
    const int bb = blockIdx.x * CHUNK;
    for (int k = t; k < NBK; k += 1024) h[k] = 0;
    __syncthreads();
#pragma unroll 4
    for (int k = 0; k < CHUNK / 1024; ++k) {
        int i = bb + k * 1024 + t;
        if (i < E) atomicAdd(&h[dstA[i] / BN], 1);
    }
    __syncthreads();
    for (int k = t; k < NBK; k += 1024) {
        int cc = h[k];
        if (cc) h[k] = atomicAdd(&cur[k], cc);   // count -> global cursor base
    }
    __syncthreads();
    const uint INVB = bf16_of(-3e30f);
    for (int k = 0; k < CHUNK / 1024; ++k) {
        int i = bb + k * 1024 + t;
        if (i >= E) continue;
        int d = dstA[i];
        int b = d / BN;
        int pos = atomicAdd(&h[b], 1);
        float4 dv = dh[i];
        float4 mv = mk[i];
        uint e0 = (mv.x > 0.5f) ? bf16_of(dv.x * mv.x) : INVB;
        uint e1 = (mv.y > 0.5f) ? bf16_of(dv.y * mv.y) : INVB;
        uint e2 = (mv.z > 0.5f) ? bf16_of(dv.z * mv.z) : INVB;
        uint e3 = (mv.w > 0.5f) ? bf16_of(dv.w * mv.w) : INVB;
        uint4 r;
        r.x = (uint)srcA[i];
        r.y = (uint)(d - b * BN);
        r.z = e0 | (e1 << 16);
        r.w = e2 | (e3 << 16);
        recs[pos] = r;
    }
}

// -------------------------------------------------------------- level kernel
// One block per bucket (125 nodes), 512 threads. Pass A: gather at[src] once,
// compute 4 candidates, stash in statically-indexed registers, LDS atomicMax.
// Pass B: from stash only, LDS atomicAdd of exp((v-m)/tau). Tails (j beyond
// KPT*512) re-read; statistically never taken (cnt <= 1536 at +16 sigma).
__global__ __launch_bounds__(512) void k_level(
        const uint4* __restrict__ recs, const int* __restrict__ base,
        float* __restrict__ at, int lvl) {
    int b = lvl * GPL + blockIdx.x;
    int j0 = base[b], j1 = base[b + 1];
    __shared__ uint  lm[BN * 2];
    __shared__ float ls[BN * 2];
    int t = threadIdx.x;
    for (int k = t; k < BN * 2; k += 512) { lm[k] = 0u; ls[k] = 0.f; }
    __syncthreads();

    float cr0[KPT], cr1[KPT], cf0[KPT], cf1[KPT];
    int nn[KPT];
#pragma unroll
    for (int k = 0; k < KPT; ++k) {
        int j = j0 + k * 512 + t;
        nn[k] = -1;
        if (j < j1) {
            uint4 r = recs[j];
            float2 a = *(const float2*)(at + 2 * (size_t)r.x);
            cr0[k] = a.x + f_of_bf16(r.z);
            cf0[k] = a.x + f_of_bf16(r.z >> 16);
            cr1[k] = a.y + f_of_bf16(r.w);
            cf1[k] = a.y + f_of_bf16(r.w >> 16);
            int n2 = 2 * (int)r.y;
            nn[k] = n2;
            atomicMax(&lm[n2],     max(enc_f(cr0[k]), enc_f(cr1[k])));
            atomicMax(&lm[n2 + 1], max(enc_f(cf0[k]), enc_f(cf1[k])));
        }
    }
    for (int j = j0 + KPT * 512 + t; j < j1; j += 512) {   // cold tail
        uint4 r = recs[j];
        float2 a = *(const float2*)(at + 2 * (size_t)r.x);
        int n2 = 2 * (int)r.y;
        atomicMax(&lm[n2],     max(enc_f(a.x + f_of_bf16(r.z)),
                                   enc_f(a.y + f_of_bf16(r.w))));
        atomicMax(&lm[n2 + 1], max(enc_f(a.x + f_of_bf16(r.z >> 16)),
                                   enc_f(a.y + f_of_bf16(r.w >> 16))));
    }
    __syncthreads();

#pragma unroll
    for (int k = 0; k < KPT; ++k) {
        if (nn[k] >= 0) {
            float mr = dec_f(lm[nn[k]]);
            atomicAdd(&ls[nn[k]], __expf((cr0[k] - mr) * INV_TAU) +
                                  __expf((cr1[k] - mr) * INV_TAU));
            float mf = dec_f(lm[nn[k] + 1]);
            atomicAdd(&ls[nn[k] + 1], __expf((cf0[k] - mf) * INV_TAU) +
                                      __expf((cf1[k] - mf) * INV_TAU));
        }
    }
    for (int j = j0 + KPT * 512 + t; j < j1; j += 512) {   // cold tail
        uint4 r = recs[j];
        float2 a = *(const float2*)(at + 2 * (size_t)r.x);
        int n2 = 2 * (int)r.y;
        float mr = dec_f(lm[n2]);
        atomicAdd(&ls[n2], __expf((a.x + f_of_bf16(r.z) - mr) * INV_TAU) +
                           __expf((a.y + f_of_bf16(r.w) - mr) * INV_TAU));
        float mf = dec_f(lm[n2 + 1]);
        atomicAdd(&ls[n2 + 1], __expf((a.x + f_of_bf16(r.z >> 16) - mf) * INV_TAU) +
                               __expf((a.y + f_of_bf16(r.w >> 16) - mf) * INV_TAU));
    }
    __syncthreads();

    size_t obase = (size_t)b * (BN * 2);
    for (int k = t; k < BN * 2; k += 512) {
        uint e = lm[k];
        float v = NEG_INF;
        if (e != 0u) {
            float m = dec_f(e);
            if (m > -1e29f) v = m + TAU_F * __logf(ls[k]);
        }
        at[obase + k] = v;
    }
}

// -------------------------------------------------------------------- init
__global__ void k_init(const float2* __restrict__ ia, float2* __restrict__ at2,
                       int per) {
    int i = blockIdx.x * blockDim.x + threadIdx.x;
    if (i < per) at2[i] = ia[i];
}

// ---------------------------------------------------------------- endpoints
__global__ void k_ep(const float2* __restrict__ at2, const int* __restrict__ ep,
                     const float* __restrict__ rat, int M,
                     float* __restrict__ out_ep, float* __restrict__ out_slack) {
    int i = blockIdx.x * blockDim.x + threadIdx.x;
    int st = gridDim.x * blockDim.x;
    const float thr = NEG_INF + 1.0f;   // == -1e30f in fp32
    for (; i < M; i += st) {
        float2 a = at2[ep[i]];
        float sx = (a.x > thr) ? a.x : 0.f;
        float sy = (a.y > thr) ? a.y : 0.f;
        out_ep[2 * i]        = sx;
        out_ep[2 * i + 1]    = sy;
        out_slack[2 * i]     = rat[2 * i]     - sx;
        out_slack[2 * i + 1] = rat[2 * i + 1] - sy;
    }
}

extern "C" void kernel_launch(void* const* d_in, const int* in_sizes, int n_in,
                              void* d_out, int out_size, void* d_ws, size_t ws_size,
                              hipStream_t stream) {
    const float* d_hat         = (const float*)d_in[0];
    const float* sta_mask      = (const float*)d_in[1];
    const float* input_arrival = (const float*)d_in[2];
    const float* rat_true      = (const float*)d_in[3];
    const int*   edge_src      = (const int*)d_in[4];
    const int*   edge_dst      = (const int*)d_in[5];
    const int*   endpoint_ids  = (const int*)d_in[6];

    const int E = in_sizes[4];
    const int N = in_sizes[2] / 2;
    const int M = in_sizes[3] / 2;
    const int L = 32;                 // max_level = 31
    const int per = N / L;
    (void)n_in; (void)out_size; (void)ws_size;

    char* ws = (char*)d_ws;
    size_t off = 0;
    auto alloc = [&](size_t bytes) {
        void* p = ws + off;
        off = (off + bytes + 255) & ~((size_t)255);
        return p;
    };
    int*   cnt  = (int*)alloc((size_t)NBK * 4);
    int*   base = (int*)alloc((size_t)(NBK + 1) * 4);
    int*   cur  = (int*)alloc((size_t)NBK * 4);
    uint4* recs = (uint4*)alloc((size_t)E * 16);   // 128 MB, packed exactly

    float* at        = (float*)d_out;              // at_all doubles as state
    float* out_ep    = at + 2 * (size_t)N;
    float* out_slack = out_ep + 2 * (size_t)M;

    hipMemsetAsync(cnt, 0, (size_t)NBK * 4, stream);
    k_init<<<(per + 255) / 256, 256, 0, stream>>>((const float2*)input_arrival,
                                                  (float2*)at, per);
    k_hist<<<1024, 256, 0, stream>>>(edge_dst, E, cnt);
    k_scan<<<1, 1024, 0, stream>>>(cnt, base, cur);

    int nChunk = (E + CHUNK - 1) / CHUNK;
    k_stage1<<<nChunk, 1024, 0, stream>>>(edge_src, edge_dst,
                                          (const float4*)d_hat, (const float4*)sta_mask,
                                          E, cur, recs);

    for (int lvl = 1; lvl < L; ++lvl)
        k_level<<<GPL, 512, 0, stream>>>(recs, base, at, lvl);

    k_ep<<<(M + 255) / 256, 256, 0, stream>>>((const float2*)at, endpoint_ids,
                                              rat_true, M, out_ep, out_slack);
}